// Round 3
// baseline (4192.468 us; speedup 1.0000x reference)
//
#include <hip/hip_runtime.h>

#define T_STEPS 1000
#define IN 13
#define HID 32

// ---------- double-precision exp, |u| <= 30, rel err ~3e-10 ----------
__device__ __forceinline__ double exp_d(double u) {
    const double INV_LN2 = 1.4426950408889634074;
    const double LN2_HI  = 6.93147180369123816490e-01;  // 32 high bits of ln2
    const double LN2_LO  = 1.90821492927058770002e-10;
    const double MAGIC   = 6755399441055744.0;          // 1.5 * 2^52
    double s  = fma(u, INV_LN2, MAGIC);                 // n encoded in mantissa
    int    n  = (int)__double2loint(s);
    double nd = s - MAGIC;                              // exact integer double
    double r  = fma(nd, -LN2_HI, u);
    r = fma(nd, -LN2_LO, r);                            // |r| <= 0.3466
    double p = 2.4801587301587301587e-5;                // 1/8!
    p = fma(p, r, 1.9841269841269841270e-4);            // 1/7!
    p = fma(p, r, 1.3888888888888888889e-3);            // 1/6!
    p = fma(p, r, 8.3333333333333333333e-3);            // 1/5!
    p = fma(p, r, 4.1666666666666666667e-2);            // 1/4!
    p = fma(p, r, 1.6666666666666666667e-1);            // 1/3!
    p = fma(p, r, 0.5);
    p = fma(p, r, 1.0);
    p = fma(p, r, 1.0);
    // scale by 2^n via exponent field (n in [-44,44], p in [0.7,1.42])
    return __hiloint2double(__double2hiint(p) + (n << 20), __double2loint(p));
}

__device__ __forceinline__ double sigmoid_d(double x) {
    double u = fmin(fmax(-x, -30.0), 30.0);
    double e = exp_d(u);
    double d = 1.0 + e;
    double r0 = (double)__builtin_amdgcn_rcpf((float)d);
    return r0 * fma(-d, r0, 2.0);                       // 1 Newton step: ~1e-14 rel
}

// gates -> (c,h). Lane k<32: slot1=i[k], slot2=g[k]; lane 32+j: slot1=f[j], slot2=o[j].
// Both half-waves redundantly maintain c[j],h[j] (identical arithmetic, no divergence).
__device__ __forceinline__ void lstm_cell_d(double a1, double a2, bool lo, double& c, double& h) {
    double s1 = sigmoid_d(a1);                          // sigma(i) | sigma(f)
    double s2 = sigmoid_d(lo ? (a2 + a2) : a2);
    s2 = lo ? fma(2.0, s2, -1.0) : s2;                  // tanh(g) | sigma(o)
    double t1 = __shfl_xor(s1, 32);
    double t2 = __shfl_xor(s2, 32);
    double ig = lo ? s1 : t1;
    double gg = lo ? s2 : t2;
    double fg = lo ? t1 : s1;
    double og = lo ? t2 : s2;
    c = fma(fg, c, ig * gg);
    double th = fma(2.0, sigmoid_d(c + c), -1.0);       // tanh(c), exact in double
    h = og * th;
}

// dual-row f64 dot against broadcast 32-vector in LDS (same-address reads: conflict-free)
__device__ __forceinline__ void dot32x2_d(const double (&w1)[HID], const double (&w2)[HID],
                                          const double* hs, double& a1, double& a2) {
    #pragma unroll
    for (int q = 0; q < HID / 2; ++q) {
        double2 h2 = *reinterpret_cast<const double2*>(&hs[q * 2]);
        a1 = fma(w1[q*2+0], h2.x, a1); a2 = fma(w2[q*2+0], h2.x, a2);
        a1 = fma(w1[q*2+1], h2.y, a1); a2 = fma(w2[q*2+1], h2.y, a2);
    }
}

__global__ __launch_bounds__(64, 1)
void lstm_fused(const float* __restrict__ X,
                const float* __restrict__ Wih0, const float* __restrict__ Whh0,
                const float* __restrict__ bih0, const float* __restrict__ bhh0,
                const float* __restrict__ Wih1, const float* __restrict__ Whh1,
                const float* __restrict__ bih1, const float* __restrict__ bhh1,
                const float* __restrict__ Wc1,  const float* __restrict__ bc1,
                const float* __restrict__ Wc2,  const float* __restrict__ bc2,
                float* __restrict__ out)
{
    const int b    = blockIdx.x;      // one wave (=one block) per batch element
    const int lane = threadIdx.x;     // 0..63
    const int r1   = lane;            // gate row 1 (i|f)
    const int r2   = lane + 64;       // gate row 2 (g|o)
    const int j32  = lane & 31;
    const bool lo  = lane < 32;

    // LDS: Wih0 rows in f64 (saves 52 VGPRs; stride 26 words -> 2-way bank alias = free)
    __shared__ __align__(16) double wx_lds[128 * IN];   // 13312 B
    __shared__ __align__(16) double h0s[HID];
    __shared__ __align__(16) double h1s[HID];
    __shared__ __align__(16) float  xs[2][64];          // 4 timesteps (52 floats) per buffer

    // ---- weights into registers as f64 (per-lane rows): 384 VGPRs ----
    double wa1[HID], wa2[HID];   // Whh0
    double wb1[HID], wb2[HID];   // Wih1
    double wr1[HID], wr2[HID];   // Whh1
    #pragma unroll
    for (int j = 0; j < HID; ++j) {
        wa1[j] = (double)Whh0[r1*HID + j]; wa2[j] = (double)Whh0[r2*HID + j];
        wb1[j] = (double)Wih1[r1*HID + j]; wb2[j] = (double)Wih1[r2*HID + j];
        wr1[j] = (double)Whh1[r1*HID + j]; wr2[j] = (double)Whh1[r2*HID + j];
    }
    #pragma unroll
    for (int i = 0; i < IN; ++i) {
        wx_lds[r1*IN + i] = (double)Wih0[r1*IN + i];
        wx_lds[r2*IN + i] = (double)Wih0[r2*IN + i];
    }
    const double b01 = (double)bih0[r1] + (double)bhh0[r1];
    const double b02 = (double)bih0[r2] + (double)bhh0[r2];
    const double b11 = (double)bih1[r1] + (double)bhh1[r1];
    const double b12 = (double)bih1[r2] + (double)bhh1[r2];

    // ---- init state ----
    if (lo) { h0s[j32] = 0.0; h1s[j32] = 0.0; }
    double c0 = 0.0, c1 = 0.0;

    const float* xb = X + (size_t)b * (T_STEPS * IN);
    const double* wrow1 = &wx_lds[r1 * IN];
    const double* wrow2 = &wx_lds[r2 * IN];

    // ---- x prefetch: groups of 4 steps (52 floats), distance 2 groups ----
    float xnext = 0.f;
    if (lane < 52) {
        xs[0][lane] = xb[lane];
        xnext       = xb[52 + lane];
    }

    #pragma unroll 1
    for (int t = 0; t < T_STEPS; ++t) {
        const int phase = t & 3;
        const int buf   = (t >> 2) & 1;
        if (phase == 0) {
            if (lane < 52) xs[buf ^ 1][lane] = xnext;
            const int base = (t + 8) * IN;
            if (base + 52 <= T_STEPS * IN && lane < 52) xnext = xb[base + lane];
        }
        const float* xt = &xs[buf][phase * IN];

        // -------- layer 0 --------
        double a1 = b01, a2 = b02;
        #pragma unroll
        for (int i = 0; i < IN; ++i) {
            double xi = (double)xt[i];
            a1 = fma(wrow1[i], xi, a1);
            a2 = fma(wrow2[i], xi, a2);
        }
        dot32x2_d(wa1, wa2, h0s, a1, a2);

        double h0v;
        lstm_cell_d(a1, a2, lo, c0, h0v);
        if (lo) h0s[j32] = h0v;

        // -------- layer 1 --------
        double g1 = b11, g2 = b12;
        dot32x2_d(wb1, wb2, h0s, g1, g2);   // input contribution (h0 at t)
        dot32x2_d(wr1, wr2, h1s, g1, g2);   // recurrent contribution (h1 at t-1)

        double h1v;
        lstm_cell_d(g1, g2, lo, c1, h1v);
        if (lo) h1s[j32] = h1v;
    }

    // ---- head: hidden = relu(h1 @ Wc1^T + bc1); out = hidden @ Wc2^T + bc2 (f64) ----
    double acc = (double)bc1[j32];
    #pragma unroll
    for (int j = 0; j < HID; ++j) acc = fma((double)Wc1[j32*HID + j], h1s[j], acc);
    double hid = fmax(acc, 0.0);   // lanes>=32 duplicate lanes<32 (identical values)

    #pragma unroll
    for (int c = 0; c < 3; ++c) {
        double v = lo ? hid * (double)Wc2[c*HID + j32] : 0.0;
        #pragma unroll
        for (int off = 32; off >= 1; off >>= 1) v += __shfl_xor(v, off);
        if (lane == 0) out[b * 3 + c] = (float)(v + (double)bc2[c]);
    }
}

extern "C" void kernel_launch(void* const* d_in, const int* in_sizes, int n_in,
                              void* d_out, int out_size, void* d_ws, size_t ws_size,
                              hipStream_t stream) {
    const float* X    = (const float*)d_in[0];
    const float* Wih0 = (const float*)d_in[1];
    const float* Whh0 = (const float*)d_in[2];
    const float* bih0 = (const float*)d_in[3];
    const float* bhh0 = (const float*)d_in[4];
    const float* Wih1 = (const float*)d_in[5];
    const float* Whh1 = (const float*)d_in[6];
    const float* bih1 = (const float*)d_in[7];
    const float* bhh1 = (const float*)d_in[8];
    const float* Wc1  = (const float*)d_in[9];
    const float* bc1  = (const float*)d_in[10];
    const float* Wc2  = (const float*)d_in[11];
    const float* bc2  = (const float*)d_in[12];

    lstm_fused<<<2048, 64, 0, stream>>>(X, Wih0, Whh0, bih0, bhh0,
                                        Wih1, Whh1, bih1, bhh1,
                                        Wc1, bc1, Wc2, bc2, (float*)d_out);
}

// Round 4
// 2991.637 us; speedup vs baseline: 1.4014x; 1.4014x over previous
//
#include <hip/hip_runtime.h>

#define T_STEPS 1000
#define IN 13
#define HID 32
#define GRPSTEPS 4
#define GRPFLOATS (GRPSTEPS * IN)                 // 52
#define NGRP (T_STEPS / GRPSTEPS)                 // 250

// ---------- double-precision exp/sigmoid — IDENTICAL numerics to R3 (absmax==0) ----------
__device__ __forceinline__ double exp_d(double u) {
    const double INV_LN2 = 1.4426950408889634074;
    const double LN2_HI  = 6.93147180369123816490e-01;
    const double LN2_LO  = 1.90821492927058770002e-10;
    const double MAGIC   = 6755399441055744.0;          // 1.5 * 2^52
    double s  = fma(u, INV_LN2, MAGIC);
    int    n  = (int)__double2loint(s);
    double nd = s - MAGIC;
    double r  = fma(nd, -LN2_HI, u);
    r = fma(nd, -LN2_LO, r);
    double p = 2.4801587301587301587e-5;
    p = fma(p, r, 1.9841269841269841270e-4);
    p = fma(p, r, 1.3888888888888888889e-3);
    p = fma(p, r, 8.3333333333333333333e-3);
    p = fma(p, r, 4.1666666666666666667e-2);
    p = fma(p, r, 1.6666666666666666667e-1);
    p = fma(p, r, 0.5);
    p = fma(p, r, 1.0);
    p = fma(p, r, 1.0);
    return __hiloint2double(__double2hiint(p) + (n << 20), __double2loint(p));
}

__device__ __forceinline__ double sigmoid_d(double x) {
    double u = fmin(fmax(-x, -30.0), 30.0);
    double e = exp_d(u);
    double d = 1.0 + e;
    double r0 = (double)__builtin_amdgcn_rcpf((float)d);
    return r0 * fma(-d, r0, 2.0);
}

// sigmoid or tanh (tanh(x) = 2*sigmoid(2x)-1), branch-free per-lane constant role
__device__ __forceinline__ double act_fn(double x, bool istanh) {
    double pre = istanh ? (x + x) : x;
    double sv  = sigmoid_d(pre);
    return istanh ? fma(2.0, sv, -1.0) : sv;
}

// Block = 256 threads = 4 waves, handles TWO batch elements (eA, eA+1).
// Waves 0,1: layer0 (units 0..15 / 16..31), lane = 4*u_local + gate (i,f,g,o).
// Waves 2,3: layer1. Software pipeline: at iter k, L0 computes h0[k], L1 computes
// h1[k-1] from h0[k-1] (LDS, double-buffered) -> ONE barrier per iteration.
__global__ __launch_bounds__(256, 2)
void lstm_fused(const float* __restrict__ X,
                const float* __restrict__ Wih0, const float* __restrict__ Whh0,
                const float* __restrict__ bih0, const float* __restrict__ bhh0,
                const float* __restrict__ Wih1, const float* __restrict__ Whh1,
                const float* __restrict__ bih1, const float* __restrict__ bhh1,
                const float* __restrict__ Wc1,  const float* __restrict__ bc1,
                const float* __restrict__ Wc2,  const float* __restrict__ bc2,
                float* __restrict__ out)
{
    const int tid  = threadIdx.x;
    const int wave = tid >> 6;
    const int lane = tid & 63;
    const bool isL1 = (wave >= 2);
    const int u    = ((wave & 1) << 4) + (lane >> 2);   // unit 0..31 within layer
    const int g    = lane & 3;                          // 0=i 1=f 2=g 3=o
    const int row  = (g << 5) + u;                      // gate row 0..127
    const int eA   = blockIdx.x * 2;

    // h packed [parity][unit][elem]: one b128 broadcast feeds both elements' FMAs
    __shared__ __align__(16) double h0buf[2][HID][2];
    __shared__ __align__(16) double h1buf[2][HID][2];
    __shared__ __align__(16) double xbuf[2][GRPSTEPS][IN][2];  // x as f64, [buf][t][i][elem]
    __shared__ __align__(16) double hid[HID][2];

    // ---- per-lane weight row in registers (L0: 45 f64, L1: 64 f64 = 128 VGPR) ----
    double w0[64];
    double bias;
    if (!isL1) {
        #pragma unroll
        for (int i = 0; i < IN; ++i)  w0[i]      = (double)Wih0[row*IN + i];
        #pragma unroll
        for (int j = 0; j < HID; ++j) w0[IN + j] = (double)Whh0[row*HID + j];
        bias = (double)bih0[row] + (double)bhh0[row];
    } else {
        #pragma unroll
        for (int j = 0; j < HID; ++j) w0[j]       = (double)Wih1[row*HID + j];
        #pragma unroll
        for (int j = 0; j < HID; ++j) w0[HID + j] = (double)Whh1[row*HID + j];
        bias = (double)bih1[row] + (double)bhh1[row];
    }

    // ---- zero initial state: h0[-1] -> h0buf[1], h1[-1] -> h1buf[0] ----
    if (tid < 64)        ((double*)h0buf)[64 + tid] = 0.0;
    else if (tid < 128)  ((double*)h1buf)[tid - 64] = 0.0;

    // ---- x staging (L0 waves only: tid<104; 1 float/lane/group, f64-converted) ----
    const bool stager = (tid < 104);
    int sl_t = 0, sl_i = 0, sl_e = 0;
    const float* xg = nullptr;
    float xreg = 0.f;
    if (stager) {
        sl_e = tid / GRPFLOATS;
        int idx = tid % GRPFLOATS;
        sl_t = idx / IN;
        sl_i = idx % IN;
        xg = X + (size_t)(eA + sl_e) * (T_STEPS * IN) + idx;
        xbuf[0][sl_t][sl_i][sl_e] = (double)xg[0];      // group 0
        xreg = xg[GRPFLOATS];                           // group 1 in reg
    }
    __syncthreads();

    double cst = 0.0;   // lane g==0: c of elem A; g==1: c of elem B; g>=2: unused

    #pragma unroll 1
    for (int k = 0; k <= T_STEPS; ++k) {
        const int p   = k & 1;
        const int grp = k >> 2;
        const int ph  = k & 3;

        if (ph == 0 && stager) {
            if (grp + 1 < NGRP) xbuf[(grp + 1) & 1][sl_t][sl_i][sl_e] = (double)xreg;
            if (grp + 2 < NGRP) xreg = xg[(grp + 2) * GRPFLOATS];
        }

        const bool active = isL1 ? (k >= 1) : (k < T_STEPS);
        if (active) {
            double aAcc = bias, bAcc = bias;
            if (!isL1) {
                const double* xp = &xbuf[grp & 1][ph][0][0];
                #pragma unroll
                for (int i = 0; i < IN; ++i) {
                    double xA = xp[i*2+0], xB = xp[i*2+1];
                    aAcc = fma(w0[i], xA, aAcc);
                    bAcc = fma(w0[i], xB, bAcc);
                }
                const double* hp = &h0buf[p ^ 1][0][0];
                #pragma unroll
                for (int j = 0; j < HID; ++j) {
                    double hA = hp[j*2+0], hB = hp[j*2+1];
                    aAcc = fma(w0[IN + j], hA, aAcc);
                    bAcc = fma(w0[IN + j], hB, bAcc);
                }
            } else {
                const double* hp = &h0buf[p ^ 1][0][0];
                #pragma unroll
                for (int j = 0; j < HID; ++j) {
                    double hA = hp[j*2+0], hB = hp[j*2+1];
                    aAcc = fma(w0[j], hA, aAcc);
                    bAcc = fma(w0[j], hB, bAcc);
                }
                const double* hq = &h1buf[p ^ 1][0][0];
                #pragma unroll
                for (int j = 0; j < HID; ++j) {
                    double hA = hq[j*2+0], hB = hq[j*2+1];
                    aAcc = fma(w0[HID + j], hA, aAcc);
                    bAcc = fma(w0[HID + j], hB, bAcc);
                }
            }

            const bool istanh = (g == 2);
            double actA = act_fn(aAcc, istanh);
            double actB = act_fn(bAcc, istanh);

            // gate exchange within the 4-lane unit cluster
            double zA1 = __shfl_xor(actA, 1);   // lane g=0 sees f(A)
            double zA2 = __shfl_xor(actA, 2);   // lane g=0 sees g(A)
            double zA3 = __shfl_xor(actA, 3);   // lane g=0 sees o(A)
            double zB1 = __shfl_xor(actB, 1);   // lane g=1 sees i(B)
            double zB2 = __shfl_xor(actB, 2);   // lane g=1 sees o(B)
            double zB3 = __shfl_xor(actB, 3);   // lane g=1 sees g(B)

            // lane g==0 updates elem A's cell, lane g==1 elem B's (others: dead compute)
            const bool roleA = (g == 0);
            double fsel = roleA ? zA1 : actB;           // forget gate
            double prod = roleA ? (actA * zA2)          // i*g (A)
                                : (zB1 * zB3);          // i*g (B)
            double osel = roleA ? zA3 : zB2;            // output gate
            cst = fma(fsel, cst, prod);
            double th = act_fn(cst, true);              // tanh(c)
            double hval = osel * th;

            if (g < 2) {
                if (!isL1) h0buf[p][u][g] = hval;
                else       h1buf[p][u][g] = hval;
            }
        }
        __syncthreads();
    }

    // ---- classifier head (f64): hidden = relu(Wc1 @ h1 + bc1); out = Wc2 @ hidden + bc2
    // final h1 is h1buf[T_STEPS & 1]
    if (tid < 64) {
        const int e = tid >> 5, j = tid & 31;
        double acc = (double)bc1[j];
        #pragma unroll
        for (int jj = 0; jj < HID; ++jj)
            acc = fma((double)Wc1[j*HID + jj], h1buf[T_STEPS & 1][jj][e], acc);
        hid[j][e] = fmax(acc, 0.0);
    }
    __syncthreads();
    if (tid < 6) {
        const int e = tid / 3, c = tid % 3;
        double v = (double)bc2[c];
        #pragma unroll
        for (int j = 0; j < HID; ++j)
            v = fma((double)Wc2[c*HID + j], hid[j][e], v);
        out[(eA + e) * 3 + c] = (float)v;
    }
}

extern "C" void kernel_launch(void* const* d_in, const int* in_sizes, int n_in,
                              void* d_out, int out_size, void* d_ws, size_t ws_size,
                              hipStream_t stream) {
    const float* X    = (const float*)d_in[0];
    const float* Wih0 = (const float*)d_in[1];
    const float* Whh0 = (const float*)d_in[2];
    const float* bih0 = (const float*)d_in[3];
    const float* bhh0 = (const float*)d_in[4];
    const float* Wih1 = (const float*)d_in[5];
    const float* Whh1 = (const float*)d_in[6];
    const float* bih1 = (const float*)d_in[7];
    const float* bhh1 = (const float*)d_in[8];
    const float* Wc1  = (const float*)d_in[9];
    const float* bc1  = (const float*)d_in[10];
    const float* Wc2  = (const float*)d_in[11];
    const float* bc2  = (const float*)d_in[12];

    lstm_fused<<<1024, 256, 0, stream>>>(X, Wih0, Whh0, bih0, bhh0,
                                         Wih1, Whh1, bih1, bhh1,
                                         Wc1, bc1, Wc2, bc2, (float*)d_out);
}

// Round 5
// 2822.595 us; speedup vs baseline: 1.4853x; 1.0599x over previous
//
#include <hip/hip_runtime.h>

#define T_STEPS 1000
#define IN 13
#define HID 32
#define ELEMS 4
#define GRPSTEPS 4
#define GRPFLOATS (GRPSTEPS * IN * ELEMS)          // 208 floats per group
#define NGRP (T_STEPS / GRPSTEPS)                  // 250

// ---------- double-precision exp/sigmoid — IDENTICAL numerics to R3/R4 (absmax==0) ----------
__device__ __forceinline__ double exp_d(double u) {
    const double INV_LN2 = 1.4426950408889634074;
    const double LN2_HI  = 6.93147180369123816490e-01;
    const double LN2_LO  = 1.90821492927058770002e-10;
    const double MAGIC   = 6755399441055744.0;          // 1.5 * 2^52
    double s  = fma(u, INV_LN2, MAGIC);
    int    n  = (int)__double2loint(s);
    double nd = s - MAGIC;
    double r  = fma(nd, -LN2_HI, u);
    r = fma(nd, -LN2_LO, r);
    double p = 2.4801587301587301587e-5;
    p = fma(p, r, 1.9841269841269841270e-4);
    p = fma(p, r, 1.3888888888888888889e-3);
    p = fma(p, r, 8.3333333333333333333e-3);
    p = fma(p, r, 4.1666666666666666667e-2);
    p = fma(p, r, 1.6666666666666666667e-1);
    p = fma(p, r, 0.5);
    p = fma(p, r, 1.0);
    p = fma(p, r, 1.0);
    return __hiloint2double(__double2hiint(p) + (n << 20), __double2loint(p));
}

__device__ __forceinline__ double sigmoid_d(double x) {
    double u = fmin(fmax(-x, -30.0), 30.0);
    double e = exp_d(u);
    double d = 1.0 + e;
    double r0 = (double)__builtin_amdgcn_rcpf((float)d);
    return r0 * fma(-d, r0, 2.0);
}

__device__ __forceinline__ double act_fn(double x, bool istanh) {
    double pre = istanh ? (x + x) : x;
    double sv  = sigmoid_d(pre);
    return istanh ? fma(2.0, sv, -1.0) : sv;
}

// Block = 256 threads = 4 waves, FOUR batch elements. Waves 0,1: layer0; waves 2,3:
// layer1, software-pipelined one step behind through double-buffered LDS h.
// lane = 4*u_local + gate. Each lane: 4 dots / 4 sigmoids (independent chains = ILP),
// then a 4x4 quad transpose hands lane g the full gate set of element g -> every lane
// updates one element's cell (no dead lanes, 1 tanh(c) per element).
__global__ __launch_bounds__(256, 2)
void lstm_fused(const float* __restrict__ X,
                const float* __restrict__ Wih0, const float* __restrict__ Whh0,
                const float* __restrict__ bih0, const float* __restrict__ bhh0,
                const float* __restrict__ Wih1, const float* __restrict__ Whh1,
                const float* __restrict__ bih1, const float* __restrict__ bhh1,
                const float* __restrict__ Wc1,  const float* __restrict__ bc1,
                const float* __restrict__ Wc2,  const float* __restrict__ bc2,
                float* __restrict__ out)
{
    const int tid  = threadIdx.x;
    const int wave = tid >> 6;
    const int lane = tid & 63;
    const bool isL1 = (wave >= 2);
    const int u    = ((wave & 1) << 4) + (lane >> 2);   // unit 0..31 within layer
    const int g    = lane & 3;                          // 0=i 1=f 2=g 3=o (also elem owned)
    const int row  = (g << 5) + u;                      // gate row 0..127
    const int eA   = blockIdx.x * ELEMS;

    __shared__ __align__(16) double h0buf[2][HID][ELEMS];
    __shared__ __align__(16) double h1buf[2][HID][ELEMS];
    __shared__ __align__(16) double xbuf[2][GRPSTEPS][IN][ELEMS];
    __shared__ __align__(16) double hidbuf[HID][ELEMS];

    // ---- per-lane weight row in registers (L0: 45 f64, L1: 64 f64) ----
    double w0[64];
    double bias;
    if (!isL1) {
        #pragma unroll
        for (int i = 0; i < IN; ++i)  w0[i]      = (double)Wih0[row*IN + i];
        #pragma unroll
        for (int j = 0; j < HID; ++j) w0[IN + j] = (double)Whh0[row*HID + j];
        bias = (double)bih0[row] + (double)bhh0[row];
    } else {
        #pragma unroll
        for (int j = 0; j < HID; ++j) w0[j]       = (double)Wih1[row*HID + j];
        #pragma unroll
        for (int j = 0; j < HID; ++j) w0[HID + j] = (double)Whh1[row*HID + j];
        bias = (double)bih1[row] + (double)bhh1[row];
    }

    // ---- zero initial state: h0[-1] -> h0buf[1], h1[-1] -> h1buf[0] (128 doubles each)
    if (tid < 128)  ((double*)h0buf)[128 + tid] = 0.0;
    else            ((double*)h1buf)[tid - 128] = 0.0;

    // ---- x staging: 104 stagers (L0 waves only), float2 each, converted to f64 ----
    const bool stager = (tid < GRPFLOATS / 2);          // tid < 104
    int st0_t = 0, st0_i = 0, st0_e = 0, st1_t = 0, st1_i = 0, st1_e = 0;
    const float* xg = nullptr;
    float2 xreg = make_float2(0.f, 0.f);
    if (stager) {
        int f0 = tid * 2, f1 = tid * 2 + 1;             // flat float idx within group
        st0_e = f0 / (GRPSTEPS * IN); int r0i = f0 % (GRPSTEPS * IN);
        st0_t = r0i / IN; st0_i = r0i % IN;
        st1_e = f1 / (GRPSTEPS * IN); int r1i = f1 % (GRPSTEPS * IN);
        st1_t = r1i / IN; st1_i = r1i % IN;
        // element-local flat offset of f0 within its element's row
        xg = X + (size_t)(eA + st0_e) * (T_STEPS * IN) + (size_t)r0i;
        // NOTE: f0,f1 are consecutive and r0i even-offset 8B-aligned only if same elem;
        // 52*4=208, per-elem span 52 (even) so f0 even => same element for f0,f1.
        float2 x0 = *(const float2*)xg;                 // group 0
        xbuf[0][st0_t][st0_i][st0_e] = (double)x0.x;
        xbuf[0][st1_t][st1_i][st1_e] = (double)x0.y;
        xreg = *(const float2*)(xg + GRPSTEPS * IN);    // group 1 (per-elem stride 52)
    }
    __syncthreads();

    double cst = 0.0;   // cell state of element g (both layers' waves keep their own)

    #pragma unroll 1
    for (int k = 0; k <= T_STEPS; ++k) {
        const int p   = k & 1;
        const int grp = k >> 2;
        const int ph  = k & 3;

        if (ph == 0 && stager) {
            if (grp + 1 < NGRP) {
                xbuf[(grp + 1) & 1][st0_t][st0_i][st0_e] = (double)xreg.x;
                xbuf[(grp + 1) & 1][st1_t][st1_i][st1_e] = (double)xreg.y;
            }
            if (grp + 2 < NGRP) xreg = *(const float2*)(xg + (size_t)(grp + 2) * GRPSTEPS * IN);
        }

        const bool active = isL1 ? (k >= 1) : (k < T_STEPS);
        if (active) {
            double a0 = bias, a1 = bias, a2 = bias, a3 = bias;
            if (!isL1) {
                const double* xp = &xbuf[grp & 1][ph][0][0];
                #pragma unroll
                for (int i = 0; i < IN; ++i) {
                    double q0 = xp[i*4+0], q1 = xp[i*4+1], q2 = xp[i*4+2], q3 = xp[i*4+3];
                    a0 = fma(w0[i], q0, a0); a1 = fma(w0[i], q1, a1);
                    a2 = fma(w0[i], q2, a2); a3 = fma(w0[i], q3, a3);
                }
                const double* hp = &h0buf[p ^ 1][0][0];
                #pragma unroll
                for (int j = 0; j < HID; ++j) {
                    double q0 = hp[j*4+0], q1 = hp[j*4+1], q2 = hp[j*4+2], q3 = hp[j*4+3];
                    a0 = fma(w0[IN+j], q0, a0); a1 = fma(w0[IN+j], q1, a1);
                    a2 = fma(w0[IN+j], q2, a2); a3 = fma(w0[IN+j], q3, a3);
                }
            } else {
                const double* hp = &h0buf[p ^ 1][0][0];
                #pragma unroll
                for (int j = 0; j < HID; ++j) {
                    double q0 = hp[j*4+0], q1 = hp[j*4+1], q2 = hp[j*4+2], q3 = hp[j*4+3];
                    a0 = fma(w0[j], q0, a0); a1 = fma(w0[j], q1, a1);
                    a2 = fma(w0[j], q2, a2); a3 = fma(w0[j], q3, a3);
                }
                const double* hq = &h1buf[p ^ 1][0][0];
                #pragma unroll
                for (int j = 0; j < HID; ++j) {
                    double q0 = hq[j*4+0], q1 = hq[j*4+1], q2 = hq[j*4+2], q3 = hq[j*4+3];
                    a0 = fma(w0[HID+j], q0, a0); a1 = fma(w0[HID+j], q1, a1);
                    a2 = fma(w0[HID+j], q2, a2); a3 = fma(w0[HID+j], q3, a3);
                }
            }

            // 4 independent activations (this lane's gate, elems 0..3)
            const bool istanh = (g == 2);
            double v0 = act_fn(a0, istanh);
            double v1 = act_fn(a1, istanh);
            double v2 = act_fn(a2, istanh);
            double v3 = act_fn(a3, istanh);

            // 4x4 transpose across the lane quad: after this, v_j = gate j of elem g.
            {
                double t0 = __shfl_xor(v1, 1), t1 = __shfl_xor(v0, 1);
                double t2 = __shfl_xor(v3, 1), t3 = __shfl_xor(v2, 1);
                bool s1 = (g & 1);
                v0 = s1 ? t0 : v0;  v1 = s1 ? v1 : t1;
                v2 = s1 ? t2 : v2;  v3 = s1 ? v3 : t3;
                t0 = __shfl_xor(v2, 2); t1 = __shfl_xor(v3, 2);
                t2 = __shfl_xor(v0, 2); t3 = __shfl_xor(v1, 2);
                bool s2 = (g & 2);
                v0 = s2 ? t0 : v0;  v1 = s2 ? t1 : v1;
                v2 = s2 ? v2 : t2;  v3 = s2 ? v3 : t3;
            }
            // v0=i, v1=f, v2=g, v3=o for element g
            cst = fma(v1, cst, v0 * v2);
            double th = act_fn(cst, true);              // tanh(c)
            double hval = v3 * th;

            if (!isL1) h0buf[p][u][g] = hval;
            else       h1buf[p][u][g] = hval;
        }
        __syncthreads();
    }

    // ---- classifier head (f64): hidden = relu(Wc1 @ h1 + bc1); out = Wc2 @ hidden + bc2
    if (tid < 128) {
        const int e = tid >> 5, j = tid & 31;
        double acc = (double)bc1[j];
        #pragma unroll
        for (int jj = 0; jj < HID; ++jj)
            acc = fma((double)Wc1[j*HID + jj], h1buf[T_STEPS & 1][jj][e], acc);
        hidbuf[j][e] = fmax(acc, 0.0);
    }
    __syncthreads();
    if (tid < 3 * ELEMS) {
        const int e = tid / 3, c = tid % 3;
        double v = (double)bc2[c];
        #pragma unroll
        for (int j = 0; j < HID; ++j)
            v = fma((double)Wc2[c*HID + j], hidbuf[j][e], v);
        out[(eA + e) * 3 + c] = (float)v;
    }
}

extern "C" void kernel_launch(void* const* d_in, const int* in_sizes, int n_in,
                              void* d_out, int out_size, void* d_ws, size_t ws_size,
                              hipStream_t stream) {
    const float* X    = (const float*)d_in[0];
    const float* Wih0 = (const float*)d_in[1];
    const float* Whh0 = (const float*)d_in[2];
    const float* bih0 = (const float*)d_in[3];
    const float* bhh0 = (const float*)d_in[4];
    const float* Wih1 = (const float*)d_in[5];
    const float* Whh1 = (const float*)d_in[6];
    const float* bih1 = (const float*)d_in[7];
    const float* bhh1 = (const float*)d_in[8];
    const float* Wc1  = (const float*)d_in[9];
    const float* bc1  = (const float*)d_in[10];
    const float* Wc2  = (const float*)d_in[11];
    const float* bc2  = (const float*)d_in[12];

    lstm_fused<<<512, 256, 0, stream>>>(X, Wih0, Whh0, bih0, bhh0,
                                        Wih1, Whh1, bih1, bhh1,
                                        Wc1, bc1, Wc2, bc2, (float*)d_out);
}